// Round 1
// baseline (3922.314 us; speedup 1.0000x reference)
//
#include <hip/hip_runtime.h>
#include <math.h>

#define TPB 256

__device__ __forceinline__ float mish_f(float x) {
  // softplus = max(x,0) + log1p(exp(-|x|))  (matches jax.nn.softplus numerics)
  float sp = fmaxf(x, 0.f) + log1pf(expf(-fabsf(x)));
  return x * tanhf(sp);
}

// ---------------------------------------------------------------------------
// Generic tiled fp32 GEMM: C = alpha * (A @ B[^T]) + bias
// A: (N,K) lda; B: (K,M) ldb row-major, or TRANSB: B physically (M,K) ldb.
// Batched via strides, grid = (ceil(M/64), ceil(N/64), batch), 256 threads.
// ---------------------------------------------------------------------------
template<bool TRANSB>
__global__ __launch_bounds__(256) void gemm_kernel(
    const float* __restrict__ A, const float* __restrict__ Bm,
    const float* __restrict__ bias, float* __restrict__ C,
    int N, int M, int K, int lda, int ldb, int ldc,
    long sA, long sB, long sC, float alpha)
{
  const float* Ab = A + (long)blockIdx.z * sA;
  const float* Bb = Bm + (long)blockIdx.z * sB;
  float* Cb = C + (long)blockIdx.z * sC;
  int row0 = blockIdx.y * 64, col0 = blockIdx.x * 64;

  __shared__ float As[16][68];   // As[k][i] = A[row0+i][k0+k]
  __shared__ float Bs[16][68];   // Bs[k][j] = B[k0+k][col0+j]

  int tid = threadIdx.x;
  int tx = tid & 15, ty = tid >> 4;
  float acc[4][4] = {};

  int ar = tid >> 2;           // 0..63
  int ak = (tid & 3) * 4;      // 0,4,8,12

  for (int k0 = 0; k0 < K; k0 += 16) {
    // stage A (64 rows x 16 k)
    {
      int grow = row0 + ar;
      bool rv = grow < N;
      const float* ap = Ab + (long)grow * lda + k0 + ak;
#pragma unroll
      for (int u = 0; u < 4; ++u) {
        int kk = k0 + ak + u;
        As[ak + u][ar] = (rv && kk < K) ? ap[u] : 0.f;
      }
    }
    if (!TRANSB) {
      int bk = tid >> 4;       // 0..15
      int bj = (tid & 15) * 4;
      int gk = k0 + bk;
      bool kv = gk < K;
      const float* bp = Bb + (long)gk * ldb + col0 + bj;
#pragma unroll
      for (int u = 0; u < 4; ++u) {
        int gj = col0 + bj + u;
        Bs[bk][bj + u] = (kv && gj < M) ? bp[u] : 0.f;
      }
    } else {
      int br = tid >> 2;       // j: 0..63
      int bk = (tid & 3) * 4;
      int gj = col0 + br;
      bool jv = gj < M;
      const float* bp = Bb + (long)gj * ldb + k0 + bk;
#pragma unroll
      for (int u = 0; u < 4; ++u) {
        int kk = k0 + bk + u;
        Bs[bk + u][br] = (jv && kk < K) ? bp[u] : 0.f;
      }
    }
    __syncthreads();
#pragma unroll
    for (int k = 0; k < 16; ++k) {
      float4 a4 = *reinterpret_cast<const float4*>(&As[k][ty * 4]);
      float4 b4 = *reinterpret_cast<const float4*>(&Bs[k][tx * 4]);
      float av[4] = {a4.x, a4.y, a4.z, a4.w};
      float bv[4] = {b4.x, b4.y, b4.z, b4.w};
#pragma unroll
      for (int i = 0; i < 4; ++i)
#pragma unroll
        for (int j = 0; j < 4; ++j)
          acc[i][j] = fmaf(av[i], bv[j], acc[i][j]);
    }
    __syncthreads();
  }

#pragma unroll
  for (int i = 0; i < 4; ++i) {
    int r = row0 + ty * 4 + i;
    if (r >= N) continue;
#pragma unroll
    for (int j = 0; j < 4; ++j) {
      int c = col0 + tx * 4 + j;
      if (c >= M) continue;
      float v = acc[i][j] * alpha + (bias ? bias[c] : 0.f);
      Cb[(long)r * ldc + c] = v;
    }
  }
}

// ---------------------------------------------------------------------------
// Fused GCN layer per graph: deg count + msg aggregation in LDS, optional mish.
// hW: (N,64) = x @ W (no bias).  out = agg + hW*dinv^2 + bias  [, mish]
// grid = G blocks, 256 threads. Edge lists are per-graph contiguous slabs.
// ---------------------------------------------------------------------------
__global__ __launch_bounds__(256) void gcn_kernel(
    const float* __restrict__ hW, const int* __restrict__ src,
    const int* __restrict__ dst, const float* __restrict__ bias,
    float* __restrict__ out, int R, int EPG, int do_mish)
{
  __shared__ float agg[200 * 64];   // 51.2 KB (MAXR=200)
  __shared__ float dinv[200];
  __shared__ int cnt[200];

  int g = blockIdx.x;
  int tid = threadIdx.x;
  long base = (long)g * R * 64;
  int RF = R * 64;

  for (int idx = tid; idx < RF; idx += TPB) agg[idx] = 0.f;
  for (int r = tid; r < R; r += TPB) cnt[r] = 0;
  __syncthreads();

  long ebase = (long)g * EPG;
  int gR = g * R;
  for (int e = tid; e < EPG; e += TPB)
    atomicAdd(&cnt[dst[ebase + e] - gR], 1);
  __syncthreads();
  for (int r = tid; r < R; r += TPB) dinv[r] = rsqrtf((float)cnt[r] + 1.f);
  __syncthreads();

  int lane = tid & 63, w = tid >> 6;
  for (int e = w; e < EPG; e += 4) {
    int s = src[ebase + e] - gR;
    int d = dst[ebase + e] - gR;
    float c = dinv[s] * dinv[d];
    atomicAdd(&agg[(d << 6) | lane], hW[base + ((long)s << 6) + lane] * c);
  }
  __syncthreads();

  for (int idx = tid; idx < RF; idx += TPB) {
    int r = idx >> 6, d2 = idx & 63;
    float v = agg[idx] + hW[base + idx] * dinv[r] * dinv[r] + bias[d2];
    if (do_mish) v = mish_f(v);
    out[base + idx] = v;
  }
}

// wave-per-row softmax in place; row length R <= 256
__global__ __launch_bounds__(256) void softmax_kernel(float* __restrict__ S,
                                                      int R, long rows)
{
  long wid = (long)blockIdx.x * 4 + (threadIdx.x >> 6);
  if (wid >= rows) return;
  int lane = threadIdx.x & 63;
  float* row = S + wid * R;
  float v[4];
  float mx = -1e30f;
#pragma unroll
  for (int t = 0; t < 4; ++t) {
    int j = lane + t * 64;
    v[t] = (j < R) ? row[j] : -1e30f;
    mx = fmaxf(mx, v[t]);
  }
#pragma unroll
  for (int o = 32; o; o >>= 1) mx = fmaxf(mx, __shfl_xor(mx, o));
  float s = 0.f;
#pragma unroll
  for (int t = 0; t < 4; ++t) {
    int j = lane + t * 64;
    if (j < R) { v[t] = expf(v[t] - mx); s += v[t]; }
  }
#pragma unroll
  for (int o = 32; o; o >>= 1) s += __shfl_xor(s, o);
  float inv = 1.f / s;
#pragma unroll
  for (int t = 0; t < 4; ++t) {
    int j = lane + t * 64;
    if (j < R) row[j] = v[t] * inv;
  }
}

// out[idx] = (1/G) * sum_g S[g*RR + idx]   (deterministic aw reduction)
__global__ void meang_kernel(const float* __restrict__ S, float* __restrict__ out,
                             int RR, int G, float inv)
{
  int idx = blockIdx.x * TPB + threadIdx.x;
  if (idx >= RR) return;
  const float* p = S + idx;
  float s = 0.f;
  for (int g = 0; g < G; ++g) s += p[(long)g * RR];
  out[idx] = s * inv;
}

// per-graph mean over R rows of a (N,64) matrix. grid=G, 64 threads.
__global__ __launch_bounds__(64) void pool_mean_kernel(const float* __restrict__ X,
                                                       float* __restrict__ out, int R)
{
  int g = blockIdx.x, lane = threadIdx.x;
  const float* p = X + (long)g * R * 64 + lane;
  float s = 0.f;
  for (int r = 0; r < R; ++r) s += p[(long)r * 64];
  out[g * 64 + lane] = s * (1.f / R);
}

// per-graph mean over V gathered rows. grid=G, 64 threads.
__global__ __launch_bounds__(64) void sub_mean_kernel(const float* __restrict__ X,
                                                      const int* __restrict__ sub,
                                                      float* __restrict__ out, int V)
{
  int g = blockIdx.x, lane = threadIdx.x;
  float s = 0.f;
  for (int v = 0; v < V; ++v) {
    int idx = sub[g * V + v];
    s += X[(long)idx * 64 + lane];
  }
  out[g * 64 + lane] = s * (1.f / V);
}

// row L2-normalize (64-dim rows). grid=G, 64 threads.
__global__ __launch_bounds__(64) void norm_rows_kernel(const float* __restrict__ X,
                                                       float* __restrict__ Y)
{
  int g = blockIdx.x, lane = threadIdx.x;
  float x = X[g * 64 + lane];
  float ss = x * x;
#pragma unroll
  for (int o = 32; o; o >>= 1) ss += __shfl_xor(ss, o);
  float n = fmaxf(sqrtf(ss), 1e-12f);
  Y[g * 64 + lane] = x / n;
}

// contrastive loss term: loss += coef * (lse_i - logits_ii). grid=G rows.
__global__ __launch_bounds__(256) void closs_kernel(const float* __restrict__ An,
                                                    const float* __restrict__ Bn,
                                                    float* __restrict__ loss, int G,
                                                    float invTemp, float coef)
{
  int i = blockIdx.x;
  __shared__ float arow[64];
  __shared__ float logits[512];
  __shared__ float red[256];
  int t = threadIdx.x;
  if (t < 64) arow[t] = An[i * 64 + t];
  __syncthreads();
  for (int j = t; j < G; j += 256) {
    const float* bp = Bn + (long)j * 64;
    float d = 0.f;
#pragma unroll
    for (int k = 0; k < 64; ++k) d = fmaf(arow[k], bp[k], d);
    logits[j] = d * invTemp;
  }
  __syncthreads();
  float mx = -1e30f;
  for (int j = t; j < G; j += 256) mx = fmaxf(mx, logits[j]);
  red[t] = mx; __syncthreads();
  for (int o = 128; o; o >>= 1) { if (t < o) red[t] = fmaxf(red[t], red[t + o]); __syncthreads(); }
  mx = red[0]; __syncthreads();
  float s = 0.f;
  for (int j = t; j < G; j += 256) s += expf(logits[j] - mx);
  red[t] = s; __syncthreads();
  for (int o = 128; o; o >>= 1) { if (t < o) red[t] += red[t + o]; __syncthreads(); }
  if (t == 0) {
    float lse = mx + logf(red[0]);
    atomicAdd(loss, coef * (lse - logits[i]));
  }
}

// head: out = mish(concat(s1,z1,s2,z2) @ fc1a + b) @ fc1b + b2. grid=G, 128 thr.
__global__ __launch_bounds__(128) void head_kernel(
    const float* __restrict__ s1, const float* __restrict__ z1,
    const float* __restrict__ s2, const float* __restrict__ z2,
    const float* __restrict__ W1, const float* __restrict__ b1,
    const float* __restrict__ W2, const float* __restrict__ b2,
    float* __restrict__ out)
{
  int g = blockIdx.x, t = threadIdx.x;
  __shared__ float feat[256];
  __shared__ float hid[128];
  if (t < 64) {
    feat[t]       = s1[g * 64 + t];
    feat[64 + t]  = z1[g * 64 + t];
    feat[128 + t] = s2[g * 64 + t];
    feat[192 + t] = z2[g * 64 + t];
  }
  __syncthreads();
  float acc = b1[t];
  for (int k = 0; k < 256; ++k) acc = fmaf(feat[k], W1[k * 128 + t], acc);
  hid[t] = mish_f(acc);
  __syncthreads();
  if (t < 2) {
    float a2 = b2[t];
#pragma unroll
    for (int k = 0; k < 128; ++k) a2 = fmaf(hid[k], W2[k * 2 + t], a2);
    out[g * 2 + t] = a2;
  }
}

// ---------------------------------------------------------------------------
static void gemm(hipStream_t st, const float* A, const float* B, const float* bias,
                 float* C, int N, int M, int K, int lda, int ldb, int ldc,
                 long sA, long sB, long sC, int batch, float alpha, bool transb)
{
  dim3 grid((M + 63) / 64, (N + 63) / 64, batch);
  if (transb)
    gemm_kernel<true><<<grid, 256, 0, st>>>(A, B, bias, C, N, M, K, lda, ldb, ldc, sA, sB, sC, alpha);
  else
    gemm_kernel<false><<<grid, 256, 0, st>>>(A, B, bias, C, N, M, K, lda, ldb, ldc, sA, sB, sC, alpha);
}

extern "C" void kernel_launch(void* const* d_in, const int* in_sizes, int n_in,
                              void* d_out, int out_size, void* d_ws, size_t ws_size,
                              hipStream_t stream)
{
  const float* x1     = (const float*)d_in[0];
  const float* x2     = (const float*)d_in[1];
  const float* fcl_W  = (const float*)d_in[2];  const float* fcl_b  = (const float*)d_in[3];
  const float* fcr_W  = (const float*)d_in[4];  const float* fcr_b  = (const float*)d_in[5];
  const float* fcl1_W = (const float*)d_in[6];  const float* fcl1_b = (const float*)d_in[7];
  const float* fcr1_W = (const float*)d_in[8];  const float* fcr1_b = (const float*)d_in[9];
  const float* a1qW = (const float*)d_in[10]; const float* a1qb = (const float*)d_in[11];
  const float* a1kW = (const float*)d_in[12]; const float* a1kb = (const float*)d_in[13];
  const float* a1vW = (const float*)d_in[14]; const float* a1vb = (const float*)d_in[15];
  const float* a2qW = (const float*)d_in[16]; const float* a2qb = (const float*)d_in[17];
  const float* a2kW = (const float*)d_in[18]; const float* a2kb = (const float*)d_in[19];
  const float* a2vW = (const float*)d_in[20]; const float* a2vb = (const float*)d_in[21];
  const float* convW  = (const float*)d_in[22]; const float* convb  = (const float*)d_in[23];
  const float* conv1W = (const float*)d_in[24]; const float* conv1b = (const float*)d_in[25];
  const float* mlpW   = (const float*)d_in[26]; const float* mlpb   = (const float*)d_in[27];
  const float* fc1aW  = (const float*)d_in[28]; const float* fc1ab  = (const float*)d_in[29];
  const float* fc1bW  = (const float*)d_in[30]; const float* fc1bb  = (const float*)d_in[31];
  const int* ei1  = (const int*)d_in[32];
  const int* ei2  = (const int*)d_in[33];
  const int* sub1 = (const int*)d_in[36];
  const int* sub2 = (const int*)d_in[37];

  const int R1 = in_sizes[6] / 128;       // 200
  const int R2 = in_sizes[8] / 128;       // 160
  const int N1 = in_sizes[34];            // 102400
  const int N2 = in_sizes[35];            // 81920
  const int G  = N1 / R1;                 // 512
  const int E1 = in_sizes[32] / 2, E2 = in_sizes[33] / 2;
  const int EPG1 = E1 / G, EPG2 = E2 / G; // 3200 / 2560
  const int V = in_sizes[36] / G;         // 64

  // workspace layout (floats)
  float* W1 = (float*)d_ws;
  size_t w1sz = (size_t)N1 * 128;
  size_t ssz  = (size_t)G * R1 * R1;
  if (ssz > w1sz) w1sz = ssz;             // W1 doubles as score buffer
  float* W2 = W1 + w1sz;
  float* W3 = W2 + (size_t)N1 * 64;
  float* W4 = W3 + (size_t)N1 * 64;
  float* W5 = W4 + (size_t)N1 * 64;
  float* Pz1 = W5 + (size_t)N1 * 64;
  float* Pz2 = Pz1 + (size_t)G * 64;
  float* Ps1 = Pz2 + (size_t)G * 64;
  float* Ps2 = Ps1 + (size_t)G * 64;
  float* Mt  = Ps2 + (size_t)G * 64;
  float* n_s1 = Mt  + (size_t)G * 64;
  float* n_z2 = n_s1 + (size_t)G * 64;
  float* n_z1 = n_z2 + (size_t)G * 64;
  float* n_s2 = n_z1 + (size_t)G * 64;

  float* loss = (float*)d_out;
  float* outp = loss + 1;
  float* aw1  = outp + (size_t)G * 2;
  float* aw2  = aw1 + (size_t)R1 * R1;

  hipMemsetAsync(d_out, 0, sizeof(float), stream);

  // ======== attention branch, side 1 ========
  gemm(stream, x1, fcl1_W, fcl1_b, W1, N1, 128, R1, R1 + 3, 128, 128, 0, 0, 0, 1, 1.f, false);
  gemm(stream, W1, a1qW, a1qb, W2, N1, 64, 128, 128, 64, 64, 0, 0, 0, 1, 1.f, false);
  gemm(stream, W1, a1kW, a1kb, W3, N1, 64, 128, 128, 64, 64, 0, 0, 0, 1, 1.f, false);
  gemm(stream, W1, a1vW, a1vb, W4, N1, 64, 128, 128, 64, 64, 0, 0, 0, 1, 1.f, false);
  // scores = Q K^T / 8, batched per graph; overwrite W1 (z1 is dead now)
  gemm(stream, W2, W3, nullptr, W1, R1, R1, 64, 64, 64, R1,
       (long)R1 * 64, (long)R1 * 64, (long)R1 * R1, G, 0.125f, true);
  {
    long rows = (long)G * R1;
    softmax_kernel<<<(int)((rows + 3) / 4), 256, 0, stream>>>(W1, R1, rows);
    meang_kernel<<<(R1 * R1 + TPB - 1) / TPB, TPB, 0, stream>>>(W1, aw1, R1 * R1, G, 1.f / G);
  }
  gemm(stream, W1, W4, nullptr, W5, R1, 64, R1, R1, 64, 64,
       (long)R1 * R1, (long)R1 * 64, (long)R1 * 64, G, 1.f, false);
  pool_mean_kernel<<<G, 64, 0, stream>>>(W5, Pz1, R1);

  // ======== attention branch, side 2 ========
  gemm(stream, x2, fcr1_W, fcr1_b, W1, N2, 128, R2, R2 + 3, 128, 128, 0, 0, 0, 1, 1.f, false);
  gemm(stream, W1, a2qW, a2qb, W2, N2, 64, 128, 128, 64, 64, 0, 0, 0, 1, 1.f, false);
  gemm(stream, W1, a2kW, a2kb, W3, N2, 64, 128, 128, 64, 64, 0, 0, 0, 1, 1.f, false);
  gemm(stream, W1, a2vW, a2vb, W4, N2, 64, 128, 128, 64, 64, 0, 0, 0, 1, 1.f, false);
  gemm(stream, W2, W3, nullptr, W1, R2, R2, 64, 64, 64, R2,
       (long)R2 * 64, (long)R2 * 64, (long)R2 * R2, G, 0.125f, true);
  {
    long rows = (long)G * R2;
    softmax_kernel<<<(int)((rows + 3) / 4), 256, 0, stream>>>(W1, R2, rows);
    meang_kernel<<<(R2 * R2 + TPB - 1) / TPB, TPB, 0, stream>>>(W1, aw2, R2 * R2, G, 1.f / G);
  }
  gemm(stream, W1, W4, nullptr, W5, R2, 64, R2, R2, 64, 64,
       (long)R2 * R2, (long)R2 * 64, (long)R2 * 64, G, 1.f, false);
  pool_mean_kernel<<<G, 64, 0, stream>>>(W5, Pz2, R2);

  // ======== GCN branch, side 1 ========
  gemm(stream, x1, fcl_W, fcl_b, W1, N1, 128, R1 + 3, R1 + 3, 128, 128, 0, 0, 0, 1, 1.f, false);
  gemm(stream, W1, convW, nullptr, W2, N1, 64, 128, 128, 64, 64, 0, 0, 0, 1, 1.f, false);
  gcn_kernel<<<G, 256, 0, stream>>>(W2, ei1, ei1 + E1, convb, W3, R1, EPG1, 1);
  gemm(stream, W3, conv1W, nullptr, W2, N1, 64, 64, 64, 64, 64, 0, 0, 0, 1, 1.f, false);
  gcn_kernel<<<G, 256, 0, stream>>>(W2, ei1, ei1 + E1, conv1b, W4, R1, EPG1, 0);
  sub_mean_kernel<<<G, 64, 0, stream>>>(W4, sub1, Mt, V);
  gemm(stream, Mt, mlpW, mlpb, Ps1, G, 64, 64, 64, 64, 64, 0, 0, 0, 1, 1.f, false);

  // ======== GCN branch, side 2 ========
  gemm(stream, x2, fcr_W, fcr_b, W1, N2, 128, R2 + 3, R2 + 3, 128, 128, 0, 0, 0, 1, 1.f, false);
  gemm(stream, W1, convW, nullptr, W2, N2, 64, 128, 128, 64, 64, 0, 0, 0, 1, 1.f, false);
  gcn_kernel<<<G, 256, 0, stream>>>(W2, ei2, ei2 + E2, convb, W3, R2, EPG2, 1);
  gemm(stream, W3, conv1W, nullptr, W2, N2, 64, 64, 64, 64, 64, 0, 0, 0, 1, 1.f, false);
  gcn_kernel<<<G, 256, 0, stream>>>(W2, ei2, ei2 + E2, conv1b, W4, R2, EPG2, 0);
  sub_mean_kernel<<<G, 64, 0, stream>>>(W4, sub2, Mt, V);
  gemm(stream, Mt, mlpW, mlpb, Ps2, G, 64, 64, 64, 64, 64, 0, 0, 0, 1, 1.f, false);

  // ======== contrastive loss + head ========
  norm_rows_kernel<<<G, 64, 0, stream>>>(Ps1, n_s1);
  norm_rows_kernel<<<G, 64, 0, stream>>>(Pz2, n_z2);
  norm_rows_kernel<<<G, 64, 0, stream>>>(Pz1, n_z1);
  norm_rows_kernel<<<G, 64, 0, stream>>>(Ps2, n_s2);
  const float invTemp = 1.f / 0.6f;
  closs_kernel<<<G, 256, 0, stream>>>(n_s1, n_z2, loss, G, invTemp, 1.f / G);
  closs_kernel<<<G, 256, 0, stream>>>(n_z1, n_s2, loss, G, invTemp, 1.f / G);

  head_kernel<<<G, 128, 0, stream>>>(Ps1, Pz1, Ps2, Pz2, fc1aW, fc1ab, fc1bW, fc1bb, outp);
}

// Round 2
// 2126.991 us; speedup vs baseline: 1.8441x; 1.8441x over previous
//
#include <hip/hip_runtime.h>
#include <math.h>

#define TPB 256
#define MAXR 200
#define MAXE 3200

__device__ __forceinline__ float mish_f(float x) {
  // softplus = max(x,0) + log1p(exp(-|x|))  (matches jax.nn.softplus numerics)
  float sp = fmaxf(x, 0.f) + log1pf(expf(-fabsf(x)));
  return x * tanhf(sp);
}

// ---------------------------------------------------------------------------
// Generic tiled fp32 GEMM: C = alpha * (A @ B[^T]) + bias
// A: (N,K) lda; B: (K,M) ldb row-major, or TRANSB: B physically (M,K) ldb.
// Batched via strides, grid = (ceil(M/64), ceil(N/64), batch), 256 threads.
// ---------------------------------------------------------------------------
template<bool TRANSB>
__global__ __launch_bounds__(256) void gemm_kernel(
    const float* __restrict__ A, const float* __restrict__ Bm,
    const float* __restrict__ bias, float* __restrict__ C,
    int N, int M, int K, int lda, int ldb, int ldc,
    long sA, long sB, long sC, float alpha)
{
  const float* Ab = A + (long)blockIdx.z * sA;
  const float* Bb = Bm + (long)blockIdx.z * sB;
  float* Cb = C + (long)blockIdx.z * sC;
  int row0 = blockIdx.y * 64, col0 = blockIdx.x * 64;

  __shared__ float As[16][68];   // As[k][i] = A[row0+i][k0+k]
  __shared__ float Bs[16][68];   // Bs[k][j] = B[k0+k][col0+j]

  int tid = threadIdx.x;
  int tx = tid & 15, ty = tid >> 4;
  float acc[4][4] = {};

  int ar = tid >> 2;           // 0..63
  int ak = (tid & 3) * 4;      // 0,4,8,12

  for (int k0 = 0; k0 < K; k0 += 16) {
    // stage A (64 rows x 16 k)
    {
      int grow = row0 + ar;
      bool rv = grow < N;
      const float* ap = Ab + (long)grow * lda + k0 + ak;
#pragma unroll
      for (int u = 0; u < 4; ++u) {
        int kk = k0 + ak + u;
        As[ak + u][ar] = (rv && kk < K) ? ap[u] : 0.f;
      }
    }
    if (!TRANSB) {
      int bk = tid >> 4;       // 0..15
      int bj = (tid & 15) * 4;
      int gk = k0 + bk;
      bool kv = gk < K;
      const float* bp = Bb + (long)gk * ldb + col0 + bj;
#pragma unroll
      for (int u = 0; u < 4; ++u) {
        int gj = col0 + bj + u;
        Bs[bk][bj + u] = (kv && gj < M) ? bp[u] : 0.f;
      }
    } else {
      int br = tid >> 2;       // j: 0..63
      int bk = (tid & 3) * 4;
      int gj = col0 + br;
      bool jv = gj < M;
      const float* bp = Bb + (long)gj * ldb + k0 + bk;
#pragma unroll
      for (int u = 0; u < 4; ++u) {
        int kk = k0 + bk + u;
        Bs[bk + u][br] = (jv && kk < K) ? bp[u] : 0.f;
      }
    }
    __syncthreads();
#pragma unroll
    for (int k = 0; k < 16; ++k) {
      float4 a4 = *reinterpret_cast<const float4*>(&As[k][ty * 4]);
      float4 b4 = *reinterpret_cast<const float4*>(&Bs[k][tx * 4]);
      float av[4] = {a4.x, a4.y, a4.z, a4.w};
      float bv[4] = {b4.x, b4.y, b4.z, b4.w};
#pragma unroll
      for (int i = 0; i < 4; ++i)
#pragma unroll
        for (int j = 0; j < 4; ++j)
          acc[i][j] = fmaf(av[i], bv[j], acc[i][j]);
    }
    __syncthreads();
  }

#pragma unroll
  for (int i = 0; i < 4; ++i) {
    int r = row0 + ty * 4 + i;
    if (r >= N) continue;
#pragma unroll
    for (int j = 0; j < 4; ++j) {
      int c = col0 + tx * 4 + j;
      if (c >= M) continue;
      float v = acc[i][j] * alpha + (bias ? bias[c] : 0.f);
      Cb[(long)r * ldc + c] = v;
    }
  }
}

// ---------------------------------------------------------------------------
// Fused GCN layer, one block per graph. Counting-sort edges by dst into CSR
// bins (LDS), stage the whole hW tile in LDS, then each wave accumulates
// complete dst rows in REGISTERS (no atomics in the hot loop).
// out[d] = dinv[d]*sum_{e:dst=d} dinv[src_e]*hW[src_e] + hW[d]*dinv[d]^2 + b
// ---------------------------------------------------------------------------
__global__ __launch_bounds__(256) void gcn_kernel(
    const float* __restrict__ hW, const int* __restrict__ src,
    const int* __restrict__ dst, const float* __restrict__ bias,
    float* __restrict__ out, int R, int EPG, int do_mish)
{
  __shared__ float hWs[MAXR * 64];        // 51.2 KB
  __shared__ float dinv_s[MAXR];
  __shared__ unsigned short ssrc[MAXE];   // 6.4 KB, src local idx < 200
  __shared__ int cnt[256];
  __shared__ int scan[256];
  __shared__ int offx[257];
  __shared__ int cur[256];

  int g = blockIdx.x, tid = threadIdx.x;
  long base = (long)g * R * 64;
  long ebase = (long)g * EPG;
  int gR = g * R;
  int RF = R * 64;

  cnt[tid] = 0;
  __syncthreads();

  // 1) in-degree count
  for (int e = tid; e < EPG; e += TPB)
    atomicAdd(&cnt[dst[ebase + e] - gR], 1);
  __syncthreads();

  // 2) inclusive Hillis-Steele scan over 256 bins -> CSR offsets
  int x = cnt[tid];
  scan[tid] = x;
  __syncthreads();
#pragma unroll
  for (int s = 1; s < 256; s <<= 1) {
    int t = (tid >= s) ? scan[tid - s] : 0;
    __syncthreads();
    scan[tid] += t;
    __syncthreads();
  }
  if (tid == 0) offx[0] = 0;
  offx[tid + 1] = scan[tid];
  cur[tid] = scan[tid] - x;            // exclusive prefix = scatter cursor
  if (tid < R) dinv_s[tid] = rsqrtf((float)cnt[tid] + 1.f);
  __syncthreads();

  // 3) scatter src indices into dst bins
  for (int e = tid; e < EPG; e += TPB) {
    int d = dst[ebase + e] - gR;
    int s = src[ebase + e] - gR;
    int pos = atomicAdd(&cur[d], 1);
    ssrc[pos] = (unsigned short)s;
  }

  // 4) stage hW tile (coalesced float4)
  for (int i = tid * 4; i < RF; i += TPB * 4)
    *reinterpret_cast<float4*>(&hWs[i]) =
        *reinterpret_cast<const float4*>(&hW[base + i]);
  __syncthreads();

  // 5) per-row register accumulation; wave w owns rows w, w+4, ...
  int lane = tid & 63, w = tid >> 6;
  for (int d = w; d < R; d += 4) {
    int i = offx[d], eEnd = offx[d + 1];
    float acc = 0.f;
    for (; i + 4 <= eEnd; i += 4) {
      int s0 = ssrc[i], s1 = ssrc[i + 1], s2 = ssrc[i + 2], s3 = ssrc[i + 3];
      float p0 = dinv_s[s0] * hWs[(s0 << 6) | lane];
      float p1 = dinv_s[s1] * hWs[(s1 << 6) | lane];
      float p2 = dinv_s[s2] * hWs[(s2 << 6) | lane];
      float p3 = dinv_s[s3] * hWs[(s3 << 6) | lane];
      acc += p0 + p1 + p2 + p3;
    }
    for (; i < eEnd; ++i) {
      int s = ssrc[i];
      acc += dinv_s[s] * hWs[(s << 6) | lane];
    }
    float di = dinv_s[d];
    float v = di * acc + hWs[(d << 6) | lane] * di * di + bias[lane];
    if (do_mish) v = mish_f(v);
    out[base + ((long)d << 6) + lane] = v;
  }
}

// wave-per-row softmax in place; row length R <= 256
__global__ __launch_bounds__(256) void softmax_kernel(float* __restrict__ S,
                                                      int R, long rows)
{
  long wid = (long)blockIdx.x * 4 + (threadIdx.x >> 6);
  if (wid >= rows) return;
  int lane = threadIdx.x & 63;
  float* row = S + wid * R;
  float v[4];
  float mx = -1e30f;
#pragma unroll
  for (int t = 0; t < 4; ++t) {
    int j = lane + t * 64;
    v[t] = (j < R) ? row[j] : -1e30f;
    mx = fmaxf(mx, v[t]);
  }
#pragma unroll
  for (int o = 32; o; o >>= 1) mx = fmaxf(mx, __shfl_xor(mx, o));
  float s = 0.f;
#pragma unroll
  for (int t = 0; t < 4; ++t) {
    int j = lane + t * 64;
    if (j < R) { v[t] = expf(v[t] - mx); s += v[t]; }
  }
#pragma unroll
  for (int o = 32; o; o >>= 1) s += __shfl_xor(s, o);
  float inv = 1.f / s;
#pragma unroll
  for (int t = 0; t < 4; ++t) {
    int j = lane + t * 64;
    if (j < R) row[j] = v[t] * inv;
  }
}

// out[idx] = (1/G) * sum_g S[g*RR + idx]   (deterministic aw reduction)
__global__ void meang_kernel(const float* __restrict__ S, float* __restrict__ out,
                             int RR, int G, float inv)
{
  int idx = blockIdx.x * TPB + threadIdx.x;
  if (idx >= RR) return;
  const float* p = S + idx;
  float s = 0.f;
  for (int g = 0; g < G; ++g) s += p[(long)g * RR];
  out[idx] = s * inv;
}

// per-graph mean over R rows of a (N,64) matrix. grid=G, 64 threads.
__global__ __launch_bounds__(64) void pool_mean_kernel(const float* __restrict__ X,
                                                       float* __restrict__ out, int R)
{
  int g = blockIdx.x, lane = threadIdx.x;
  const float* p = X + (long)g * R * 64 + lane;
  float s = 0.f;
  for (int r = 0; r < R; ++r) s += p[(long)r * 64];
  out[g * 64 + lane] = s * (1.f / R);
}

// per-graph mean over V gathered rows. grid=G, 64 threads.
__global__ __launch_bounds__(64) void sub_mean_kernel(const float* __restrict__ X,
                                                      const int* __restrict__ sub,
                                                      float* __restrict__ out, int V)
{
  int g = blockIdx.x, lane = threadIdx.x;
  float s = 0.f;
  for (int v = 0; v < V; ++v) {
    int idx = sub[g * V + v];
    s += X[(long)idx * 64 + lane];
  }
  out[g * 64 + lane] = s * (1.f / V);
}

// row L2-normalize (64-dim rows). grid=G, 64 threads.
__global__ __launch_bounds__(64) void norm_rows_kernel(const float* __restrict__ X,
                                                       float* __restrict__ Y)
{
  int g = blockIdx.x, lane = threadIdx.x;
  float x = X[g * 64 + lane];
  float ss = x * x;
#pragma unroll
  for (int o = 32; o; o >>= 1) ss += __shfl_xor(ss, o);
  float n = fmaxf(sqrtf(ss), 1e-12f);
  Y[g * 64 + lane] = x / n;
}

// contrastive loss term: loss += coef * (lse_i - logits_ii). grid=G rows.
__global__ __launch_bounds__(256) void closs_kernel(const float* __restrict__ An,
                                                    const float* __restrict__ Bn,
                                                    float* __restrict__ loss, int G,
                                                    float invTemp, float coef)
{
  int i = blockIdx.x;
  __shared__ float arow[64];
  __shared__ float logits[512];
  __shared__ float red[256];
  int t = threadIdx.x;
  if (t < 64) arow[t] = An[i * 64 + t];
  __syncthreads();
  for (int j = t; j < G; j += 256) {
    const float* bp = Bn + (long)j * 64;
    float d = 0.f;
#pragma unroll
    for (int k = 0; k < 64; ++k) d = fmaf(arow[k], bp[k], d);
    logits[j] = d * invTemp;
  }
  __syncthreads();
  float mx = -1e30f;
  for (int j = t; j < G; j += 256) mx = fmaxf(mx, logits[j]);
  red[t] = mx; __syncthreads();
  for (int o = 128; o; o >>= 1) { if (t < o) red[t] = fmaxf(red[t], red[t + o]); __syncthreads(); }
  mx = red[0]; __syncthreads();
  float s = 0.f;
  for (int j = t; j < G; j += 256) s += expf(logits[j] - mx);
  red[t] = s; __syncthreads();
  for (int o = 128; o; o >>= 1) { if (t < o) red[t] += red[t + o]; __syncthreads(); }
  if (t == 0) {
    float lse = mx + logf(red[0]);
    atomicAdd(loss, coef * (lse - logits[i]));
  }
}

// head: out = mish(concat(s1,z1,s2,z2) @ fc1a + b) @ fc1b + b2. grid=G, 128 thr.
__global__ __launch_bounds__(128) void head_kernel(
    const float* __restrict__ s1, const float* __restrict__ z1,
    const float* __restrict__ s2, const float* __restrict__ z2,
    const float* __restrict__ W1, const float* __restrict__ b1,
    const float* __restrict__ W2, const float* __restrict__ b2,
    float* __restrict__ out)
{
  int g = blockIdx.x, t = threadIdx.x;
  __shared__ float feat[256];
  __shared__ float hid[128];
  if (t < 64) {
    feat[t]       = s1[g * 64 + t];
    feat[64 + t]  = z1[g * 64 + t];
    feat[128 + t] = s2[g * 64 + t];
    feat[192 + t] = z2[g * 64 + t];
  }
  __syncthreads();
  float acc = b1[t];
  for (int k = 0; k < 256; ++k) acc = fmaf(feat[k], W1[k * 128 + t], acc);
  hid[t] = mish_f(acc);
  __syncthreads();
  if (t < 2) {
    float a2 = b2[t];
#pragma unroll
    for (int k = 0; k < 128; ++k) a2 = fmaf(hid[k], W2[k * 2 + t], a2);
    out[g * 2 + t] = a2;
  }
}

// ---------------------------------------------------------------------------
static void gemm(hipStream_t st, const float* A, const float* B, const float* bias,
                 float* C, int N, int M, int K, int lda, int ldb, int ldc,
                 long sA, long sB, long sC, int batch, float alpha, bool transb)
{
  dim3 grid((M + 63) / 64, (N + 63) / 64, batch);
  if (transb)
    gemm_kernel<true><<<grid, 256, 0, st>>>(A, B, bias, C, N, M, K, lda, ldb, ldc, sA, sB, sC, alpha);
  else
    gemm_kernel<false><<<grid, 256, 0, st>>>(A, B, bias, C, N, M, K, lda, ldb, ldc, sA, sB, sC, alpha);
}

extern "C" void kernel_launch(void* const* d_in, const int* in_sizes, int n_in,
                              void* d_out, int out_size, void* d_ws, size_t ws_size,
                              hipStream_t stream)
{
  const float* x1     = (const float*)d_in[0];
  const float* x2     = (const float*)d_in[1];
  const float* fcl_W  = (const float*)d_in[2];  const float* fcl_b  = (const float*)d_in[3];
  const float* fcr_W  = (const float*)d_in[4];  const float* fcr_b  = (const float*)d_in[5];
  const float* fcl1_W = (const float*)d_in[6];  const float* fcl1_b = (const float*)d_in[7];
  const float* fcr1_W = (const float*)d_in[8];  const float* fcr1_b = (const float*)d_in[9];
  const float* a1qW = (const float*)d_in[10]; const float* a1qb = (const float*)d_in[11];
  const float* a1kW = (const float*)d_in[12]; const float* a1kb = (const float*)d_in[13];
  const float* a1vW = (const float*)d_in[14]; const float* a1vb = (const float*)d_in[15];
  const float* a2qW = (const float*)d_in[16]; const float* a2qb = (const float*)d_in[17];
  const float* a2kW = (const float*)d_in[18]; const float* a2kb = (const float*)d_in[19];
  const float* a2vW = (const float*)d_in[20]; const float* a2vb = (const float*)d_in[21];
  const float* convW  = (const float*)d_in[22]; const float* convb  = (const float*)d_in[23];
  const float* conv1W = (const float*)d_in[24]; const float* conv1b = (const float*)d_in[25];
  const float* mlpW   = (const float*)d_in[26]; const float* mlpb   = (const float*)d_in[27];
  const float* fc1aW  = (const float*)d_in[28]; const float* fc1ab  = (const float*)d_in[29];
  const float* fc1bW  = (const float*)d_in[30]; const float* fc1bb  = (const float*)d_in[31];
  const int* ei1  = (const int*)d_in[32];
  const int* ei2  = (const int*)d_in[33];
  const int* sub1 = (const int*)d_in[36];
  const int* sub2 = (const int*)d_in[37];

  const int R1 = in_sizes[6] / 128;       // 200
  const int R2 = in_sizes[8] / 128;       // 160
  const int N1 = in_sizes[34];            // 102400
  const int N2 = in_sizes[35];            // 81920
  const int G  = N1 / R1;                 // 512
  const int E1 = in_sizes[32] / 2, E2 = in_sizes[33] / 2;
  const int EPG1 = E1 / G, EPG2 = E2 / G; // 3200 / 2560
  const int V = in_sizes[36] / G;         // 64

  // workspace layout (floats)
  float* W1 = (float*)d_ws;
  size_t w1sz = (size_t)N1 * 128;
  size_t ssz  = (size_t)G * R1 * R1;
  if (ssz > w1sz) w1sz = ssz;             // W1 doubles as score buffer
  float* W2 = W1 + w1sz;
  float* W3 = W2 + (size_t)N1 * 64;
  float* W4 = W3 + (size_t)N1 * 64;
  float* W5 = W4 + (size_t)N1 * 64;
  float* Pz1 = W5 + (size_t)N1 * 64;
  float* Pz2 = Pz1 + (size_t)G * 64;
  float* Ps1 = Pz2 + (size_t)G * 64;
  float* Ps2 = Ps1 + (size_t)G * 64;
  float* Mt  = Ps2 + (size_t)G * 64;
  float* n_s1 = Mt  + (size_t)G * 64;
  float* n_z2 = n_s1 + (size_t)G * 64;
  float* n_z1 = n_z2 + (size_t)G * 64;
  float* n_s2 = n_z1 + (size_t)G * 64;

  float* loss = (float*)d_out;
  float* outp = loss + 1;
  float* aw1  = outp + (size_t)G * 2;
  float* aw2  = aw1 + (size_t)R1 * R1;

  hipMemsetAsync(d_out, 0, sizeof(float), stream);

  // ======== attention branch, side 1 ========
  gemm(stream, x1, fcl1_W, fcl1_b, W1, N1, 128, R1, R1 + 3, 128, 128, 0, 0, 0, 1, 1.f, false);
  gemm(stream, W1, a1qW, a1qb, W2, N1, 64, 128, 128, 64, 64, 0, 0, 0, 1, 1.f, false);
  gemm(stream, W1, a1kW, a1kb, W3, N1, 64, 128, 128, 64, 64, 0, 0, 0, 1, 1.f, false);
  gemm(stream, W1, a1vW, a1vb, W4, N1, 64, 128, 128, 64, 64, 0, 0, 0, 1, 1.f, false);
  // scores = Q K^T / 8, batched per graph; overwrite W1 (z1 is dead now)
  gemm(stream, W2, W3, nullptr, W1, R1, R1, 64, 64, 64, R1,
       (long)R1 * 64, (long)R1 * 64, (long)R1 * R1, G, 0.125f, true);
  {
    long rows = (long)G * R1;
    softmax_kernel<<<(int)((rows + 3) / 4), 256, 0, stream>>>(W1, R1, rows);
    meang_kernel<<<(R1 * R1 + TPB - 1) / TPB, TPB, 0, stream>>>(W1, aw1, R1 * R1, G, 1.f / G);
  }
  gemm(stream, W1, W4, nullptr, W5, R1, 64, R1, R1, 64, 64,
       (long)R1 * R1, (long)R1 * 64, (long)R1 * 64, G, 1.f, false);
  pool_mean_kernel<<<G, 64, 0, stream>>>(W5, Pz1, R1);

  // ======== attention branch, side 2 ========
  gemm(stream, x2, fcr1_W, fcr1_b, W1, N2, 128, R2, R2 + 3, 128, 128, 0, 0, 0, 1, 1.f, false);
  gemm(stream, W1, a2qW, a2qb, W2, N2, 64, 128, 128, 64, 64, 0, 0, 0, 1, 1.f, false);
  gemm(stream, W1, a2kW, a2kb, W3, N2, 64, 128, 128, 64, 64, 0, 0, 0, 1, 1.f, false);
  gemm(stream, W1, a2vW, a2vb, W4, N2, 64, 128, 128, 64, 64, 0, 0, 0, 1, 1.f, false);
  gemm(stream, W2, W3, nullptr, W1, R2, R2, 64, 64, 64, R2,
       (long)R2 * 64, (long)R2 * 64, (long)R2 * R2, G, 0.125f, true);
  {
    long rows = (long)G * R2;
    softmax_kernel<<<(int)((rows + 3) / 4), 256, 0, stream>>>(W1, R2, rows);
    meang_kernel<<<(R2 * R2 + TPB - 1) / TPB, TPB, 0, stream>>>(W1, aw2, R2 * R2, G, 1.f / G);
  }
  gemm(stream, W1, W4, nullptr, W5, R2, 64, R2, R2, 64, 64,
       (long)R2 * R2, (long)R2 * 64, (long)R2 * 64, G, 1.f, false);
  pool_mean_kernel<<<G, 64, 0, stream>>>(W5, Pz2, R2);

  // ======== GCN branch, side 1 ========
  gemm(stream, x1, fcl_W, fcl_b, W1, N1, 128, R1 + 3, R1 + 3, 128, 128, 0, 0, 0, 1, 1.f, false);
  gemm(stream, W1, convW, nullptr, W2, N1, 64, 128, 128, 64, 64, 0, 0, 0, 1, 1.f, false);
  gcn_kernel<<<G, 256, 0, stream>>>(W2, ei1, ei1 + E1, convb, W3, R1, EPG1, 1);
  gemm(stream, W3, conv1W, nullptr, W2, N1, 64, 64, 64, 64, 64, 0, 0, 0, 1, 1.f, false);
  gcn_kernel<<<G, 256, 0, stream>>>(W2, ei1, ei1 + E1, conv1b, W4, R1, EPG1, 0);
  sub_mean_kernel<<<G, 64, 0, stream>>>(W4, sub1, Mt, V);
  gemm(stream, Mt, mlpW, mlpb, Ps1, G, 64, 64, 64, 64, 64, 0, 0, 0, 1, 1.f, false);

  // ======== GCN branch, side 2 ========
  gemm(stream, x2, fcr_W, fcr_b, W1, N2, 128, R2 + 3, R2 + 3, 128, 128, 0, 0, 0, 1, 1.f, false);
  gemm(stream, W1, convW, nullptr, W2, N2, 64, 128, 128, 64, 64, 0, 0, 0, 1, 1.f, false);
  gcn_kernel<<<G, 256, 0, stream>>>(W2, ei2, ei2 + E2, convb, W3, R2, EPG2, 1);
  gemm(stream, W3, conv1W, nullptr, W2, N2, 64, 64, 64, 64, 64, 0, 0, 0, 1, 1.f, false);
  gcn_kernel<<<G, 256, 0, stream>>>(W2, ei2, ei2 + E2, conv1b, W4, R2, EPG2, 0);
  sub_mean_kernel<<<G, 64, 0, stream>>>(W4, sub2, Mt, V);
  gemm(stream, Mt, mlpW, mlpb, Ps2, G, 64, 64, 64, 64, 64, 0, 0, 0, 1, 1.f, false);

  // ======== contrastive loss + head ========
  norm_rows_kernel<<<G, 64, 0, stream>>>(Ps1, n_s1);
  norm_rows_kernel<<<G, 64, 0, stream>>>(Pz2, n_z2);
  norm_rows_kernel<<<G, 64, 0, stream>>>(Pz1, n_z1);
  norm_rows_kernel<<<G, 64, 0, stream>>>(Ps2, n_s2);
  const float invTemp = 1.f / 0.6f;
  closs_kernel<<<G, 256, 0, stream>>>(n_s1, n_z2, loss, G, invTemp, 1.f / G);
  closs_kernel<<<G, 256, 0, stream>>>(n_z1, n_s2, loss, G, invTemp, 1.f / G);

  head_kernel<<<G, 128, 0, stream>>>(Ps1, Pz1, Ps2, Pz2, fc1aW, fc1ab, fc1bW, fc1bb, outp);
}

// Round 4
// 2067.521 us; speedup vs baseline: 1.8971x; 1.0288x over previous
//
#include <hip/hip_runtime.h>
#include <math.h>

#define TPB 256
#define MAXR 200
#define MAXE 3200

typedef float f32x4 __attribute__((ext_vector_type(4)));
typedef __bf16 bfv8 __attribute__((ext_vector_type(8)));

union U8 {
  uint4 q;
  unsigned short us[8];
  __bf16 b[8];
  bfv8 v;
};

__device__ __forceinline__ unsigned short f2bfu(float f) {
  union { __bf16 h; unsigned short u; } x;
  x.h = (__bf16)f;
  return x.u;
}
__device__ __forceinline__ float bfu2f(unsigned short u) {
  return __uint_as_float((unsigned)u << 16);
}

__device__ __forceinline__ float mish_f(float x) {
  float sp = fmaxf(x, 0.f) + log1pf(expf(-fabsf(x)));
  return x * tanhf(sp);
}

// ---------------------------------------------------------------------------
// bf16 MFMA GEMM: C = alpha * (A @ B[^T]) + bias
// A (N,K) fp32 or bf16, read per-lane direct from global (1 read per col-block).
// B staged to LDS as bf16 [n][Kpad].
// Kpad = roundup32(K)+8: (a) mfma inner loop reads shorts up to roundup32(K),
// all inside the staged zero-padded region (the R3 NaN bug was Kpad too small
// -> uninit LDS * 0 = NaN); (b) Kpad%16==8 keeps ds reads ~2-way (free, m136).
// Block: 256 thr = 4 waves; wave w: rows [w*16,w*16+16) x BM=NJ*16 cols.
// mfma_f32_16x16x32_bf16: A row=lane&15, k-slots (lane>>4)*8+j; B col=lane&15
// same k-slots; D col=lane&15, row=(lane>>4)*4+reg [m89/m91-verified].
// ---------------------------------------------------------------------------
template<bool ABF16>
__device__ __forceinline__ bfv8 load_a_frag(const float* Af, const unsigned short* Ah,
                                            bool rowok, bool avec, int kb, int K) {
  U8 u;
  if (ABF16) {
    if (rowok && kb + 8 <= K) {
      u.q = *(const uint4*)(Ah + kb);
    } else {
#pragma unroll
      for (int j = 0; j < 8; ++j) u.us[j] = (rowok && kb + j < K) ? Ah[kb + j] : 0;
    }
  } else {
    if (rowok && avec && kb + 8 <= K) {
      float4 f0 = *(const float4*)(Af + kb);
      float4 f1 = *(const float4*)(Af + kb + 4);
      u.b[0] = (__bf16)f0.x; u.b[1] = (__bf16)f0.y; u.b[2] = (__bf16)f0.z; u.b[3] = (__bf16)f0.w;
      u.b[4] = (__bf16)f1.x; u.b[5] = (__bf16)f1.y; u.b[6] = (__bf16)f1.z; u.b[7] = (__bf16)f1.w;
    } else {
#pragma unroll
      for (int j = 0; j < 8; ++j) {
        float f = (rowok && kb + j < K) ? Af[kb + j] : 0.f;
        u.b[j] = (__bf16)f;
      }
    }
  }
  return u.v;
}

template<bool TRANSB, bool ABF16, bool CBF16, int NJ, int KPMAX>
__global__ __launch_bounds__(256) void gemm_mfma(
    const void* __restrict__ Av, const float* __restrict__ Bm,
    const float* __restrict__ bias, void* __restrict__ Cv,
    int N, int M, int K, int lda, int ldb, int ldc,
    long sA, long sB, long sC, float alpha, int Kpad)
{
  constexpr int BM = NJ * 16;
  __shared__ unsigned short Bs[BM * KPMAX];

  const int tid = threadIdx.x;
  const int col0 = blockIdx.x * BM, row0 = blockIdx.y * 64;
  const float* Bb = Bm + (long)blockIdx.z * sB;

  // ---- stage B panel as bf16 (zero-padded to Kpad) ----
  if (TRANSB) {
    // B physically (M,K) row-major: Bs[n][k] = Bp[col0+n][k]
    for (int n = tid >> 2; n < BM; n += 64) {
      bool nok = (col0 + n) < M;
      const float* bp = Bb + (long)(col0 + n) * ldb;
      for (int kb = (tid & 3) * 8; kb < Kpad; kb += 32) {
        U8 u;
        if (nok && kb + 8 <= K && ((ldb & 3) == 0)) {
          float4 f0 = *(const float4*)(bp + kb);
          float4 f1 = *(const float4*)(bp + kb + 4);
          u.b[0] = (__bf16)f0.x; u.b[1] = (__bf16)f0.y; u.b[2] = (__bf16)f0.z; u.b[3] = (__bf16)f0.w;
          u.b[4] = (__bf16)f1.x; u.b[5] = (__bf16)f1.y; u.b[6] = (__bf16)f1.z; u.b[7] = (__bf16)f1.w;
        } else {
#pragma unroll
          for (int j = 0; j < 8; ++j) {
            float f = (nok && kb + j < K) ? bp[kb + j] : 0.f;
            u.b[j] = (__bf16)f;
          }
        }
        *(uint4*)&Bs[n * Kpad + kb] = u.q;
      }
    }
  } else {
    // B (K,M) row-major: Bs[n][k] = B[k][col0+n]
    for (int n = tid & 63; n < BM; n += 64) {
      bool nok = (col0 + n) < M;
      for (int k = tid >> 6; k < Kpad; k += 4) {
        float f = (nok && k < K) ? Bb[(long)k * ldb + col0 + n] : 0.f;
        Bs[n * Kpad + k] = f2bfu(f);
      }
    }
  }
  __syncthreads();

  const int lane = tid & 63, w = tid >> 6;
  const int mrow = lane & 15, kg = lane >> 4;
  const int arow = row0 + w * 16 + mrow;
  const bool rowok = arow < N;
  const bool avec = ABF16 || ((lda & 3) == 0);

  const float* Af = nullptr;
  const unsigned short* Ah = nullptr;
  if (ABF16) Ah = (const unsigned short*)Av + (long)blockIdx.z * sA + (long)arow * lda;
  else       Af = (const float*)Av + (long)blockIdx.z * sA + (long)arow * lda;

  f32x4 acc[NJ];
#pragma unroll
  for (int j = 0; j < NJ; ++j) acc[j] = (f32x4)0.f;

  bfv8 acur = load_a_frag<ABF16>(Af, Ah, rowok, avec, kg * 8, K);
  for (int k0 = 0; k0 < K; k0 += 32) {
    bfv8 anext;
    bool more = (k0 + 32) < K;
    if (more) anext = load_a_frag<ABF16>(Af, Ah, rowok, avec, k0 + 32 + kg * 8, K);
    int kb = k0 + kg * 8;
#pragma unroll
    for (int j = 0; j < NJ; ++j) {
      U8 ub;
      ub.q = *(const uint4*)&Bs[(j * 16 + mrow) * Kpad + kb];
      acc[j] = __builtin_amdgcn_mfma_f32_16x16x32_bf16(acur, ub.v, acc[j], 0, 0, 0);
    }
    if (more) acur = anext;
  }

  // ---- epilogue ----
  long cbase = (long)blockIdx.z * sC;
#pragma unroll
  for (int j = 0; j < NJ; ++j) {
    int gc = col0 + j * 16 + mrow;
    if (gc >= M) continue;
    float bb = bias ? bias[gc] : 0.f;
#pragma unroll
    for (int r = 0; r < 4; ++r) {
      int gr = row0 + w * 16 + kg * 4 + r;
      if (gr >= N) continue;
      float v = acc[j][r] * alpha + bb;
      if (CBF16) ((unsigned short*)Cv)[cbase + (long)gr * ldc + gc] = f2bfu(v);
      else       ((float*)Cv)[cbase + (long)gr * ldc + gc] = v;
    }
  }
}

// Kpad = roundup32(K) + 8  (covers all mfma B-reads; %16==8 for bank aliasing)
static inline int kpad_of(int K) {
  return ((K + 31) / 32) * 32 + 8;
}

// fp32 A, fp32 C, B (K,M): the workhorse
static void gemm_f(hipStream_t st, const float* A, const float* B, const float* bias,
                   float* C, int N, int M, int K, int lda, int ldb, int ldc,
                   long sA, long sB, long sC, int batch, float alpha)
{
  int Kp = kpad_of(K);
  if (M > 64) {
    dim3 g((M + 127) / 128, (N + 63) / 64, batch);
    if (Kp <= 136)
      gemm_mfma<false,false,false,8,136><<<g,256,0,st>>>(A,B,bias,C,N,M,K,lda,ldb,ldc,sA,sB,sC,alpha,Kp);
    else
      gemm_mfma<false,false,false,8,232><<<g,256,0,st>>>(A,B,bias,C,N,M,K,lda,ldb,ldc,sA,sB,sC,alpha,Kp);
  } else {
    dim3 g((M + 63) / 64, (N + 63) / 64, batch);
    if (Kp <= 136)
      gemm_mfma<false,false,false,4,136><<<g,256,0,st>>>(A,B,bias,C,N,M,K,lda,ldb,ldc,sA,sB,sC,alpha,Kp);
    else
      gemm_mfma<false,false,false,4,232><<<g,256,0,st>>>(A,B,bias,C,N,M,K,lda,ldb,ldc,sA,sB,sC,alpha,Kp);
  }
}

// scores: fp32 A (Q), TRANSB fp32 B (K-matrix), bf16 C
static void gemm_scores(hipStream_t st, const float* Q, const float* Km,
                        unsigned short* S, int R, int ld, int batch, float alpha)
{
  int Kp = kpad_of(64);  // 72
  dim3 g((R + 127) / 128, (R + 63) / 64, batch);
  gemm_mfma<true,false,true,8,72><<<g,256,0,st>>>(Q,Km,nullptr,S,R,R,64,ld,ld,R,
      (long)R*ld,(long)R*ld,(long)R*R,alpha,Kp);
}

// PV: bf16 A (S), fp32 B (V), fp32 C
static void gemm_pv(hipStream_t st, const unsigned short* S, const float* V,
                    float* C, int R, int ldv, int batch)
{
  int Kp = kpad_of(R);
  dim3 g(1, (R + 63) / 64, batch);
  gemm_mfma<false,true,false,4,232><<<g,256,0,st>>>(S,V,nullptr,C,R,64,R,R,ldv,64,
      (long)R*R,(long)R*ldv,(long)R*64,1.f,Kp);
}

// concat q|k|v weights (Krows x Mc each) into W (Krows x 3Mc) + bias
__global__ void concat3_kernel(const float* __restrict__ q, const float* __restrict__ k,
                               const float* __restrict__ v, float* __restrict__ W,
                               const float* __restrict__ qb, const float* __restrict__ kb,
                               const float* __restrict__ vb, float* __restrict__ b,
                               int Krows, int Mc)
{
  int idx = blockIdx.x * TPB + threadIdx.x;
  int tot = Krows * 3 * Mc;
  if (idx < tot) {
    int r = idx / (3 * Mc), c = idx % (3 * Mc);
    float val = (c < Mc) ? q[r * Mc + c] : (c < 2 * Mc) ? k[r * Mc + c - Mc] : v[r * Mc + c - 2 * Mc];
    W[idx] = val;
  }
  if (idx < 3 * Mc)
    b[idx] = (idx < Mc) ? qb[idx] : (idx < 2 * Mc) ? kb[idx - Mc] : vb[idx - 2 * Mc];
}

// ---------------------------------------------------------------------------
// GCN (R2-verified): counting-sort edges by dst, hW tile in LDS, register rows.
// ---------------------------------------------------------------------------
__global__ __launch_bounds__(256) void gcn_kernel(
    const float* __restrict__ hW, const int* __restrict__ src,
    const int* __restrict__ dst, const float* __restrict__ bias,
    float* __restrict__ out, int R, int EPG, int do_mish)
{
  __shared__ float hWs[MAXR * 64];
  __shared__ float dinv_s[MAXR];
  __shared__ unsigned short ssrc[MAXE];
  __shared__ int cnt[256];
  __shared__ int scan[256];
  __shared__ int offx[257];
  __shared__ int cur[256];

  int g = blockIdx.x, tid = threadIdx.x;
  long base = (long)g * R * 64;
  long ebase = (long)g * EPG;
  int gR = g * R;
  int RF = R * 64;

  cnt[tid] = 0;
  __syncthreads();
  for (int e = tid; e < EPG; e += TPB)
    atomicAdd(&cnt[dst[ebase + e] - gR], 1);
  __syncthreads();

  int x = cnt[tid];
  scan[tid] = x;
  __syncthreads();
#pragma unroll
  for (int s = 1; s < 256; s <<= 1) {
    int t = (tid >= s) ? scan[tid - s] : 0;
    __syncthreads();
    scan[tid] += t;
    __syncthreads();
  }
  if (tid == 0) offx[0] = 0;
  offx[tid + 1] = scan[tid];
  cur[tid] = scan[tid] - x;
  if (tid < R) dinv_s[tid] = rsqrtf((float)cnt[tid] + 1.f);
  __syncthreads();

  for (int e = tid; e < EPG; e += TPB) {
    int d = dst[ebase + e] - gR;
    int s = src[ebase + e] - gR;
    int pos = atomicAdd(&cur[d], 1);
    ssrc[pos] = (unsigned short)s;
  }
  for (int i = tid * 4; i < RF; i += TPB * 4)
    *reinterpret_cast<float4*>(&hWs[i]) =
        *reinterpret_cast<const float4*>(&hW[base + i]);
  __syncthreads();

  int lane = tid & 63, w = tid >> 6;
  for (int d = w; d < R; d += 4) {
    int i = offx[d], eEnd = offx[d + 1];
    float acc = 0.f;
    for (; i + 4 <= eEnd; i += 4) {
      int s0 = ssrc[i], s1 = ssrc[i + 1], s2 = ssrc[i + 2], s3 = ssrc[i + 3];
      float p0 = dinv_s[s0] * hWs[(s0 << 6) | lane];
      float p1 = dinv_s[s1] * hWs[(s1 << 6) | lane];
      float p2 = dinv_s[s2] * hWs[(s2 << 6) | lane];
      float p3 = dinv_s[s3] * hWs[(s3 << 6) | lane];
      acc += p0 + p1 + p2 + p3;
    }
    for (; i < eEnd; ++i) {
      int s = ssrc[i];
      acc += dinv_s[s] * hWs[(s << 6) | lane];
    }
    float di = dinv_s[d];
    float v = di * acc + hWs[(d << 6) | lane] * di * di + bias[lane];
    if (do_mish) v = mish_f(v);
    out[base + ((long)d << 6) + lane] = v;
  }
}

// wave-per-row softmax in place on bf16; row length R <= 256
__global__ __launch_bounds__(256) void softmax_bf16(unsigned short* __restrict__ S,
                                                    int R, long rows)
{
  long wid = (long)blockIdx.x * 4 + (threadIdx.x >> 6);
  if (wid >= rows) return;
  int lane = threadIdx.x & 63;
  unsigned short* row = S + wid * R;
  float v[4];
  float mx = -1e30f;
#pragma unroll
  for (int t = 0; t < 4; ++t) {
    int j = lane + t * 64;
    v[t] = (j < R) ? bfu2f(row[j]) : -1e30f;
    mx = fmaxf(mx, v[t]);
  }
#pragma unroll
  for (int o = 32; o; o >>= 1) mx = fmaxf(mx, __shfl_xor(mx, o));
  float s = 0.f;
#pragma unroll
  for (int t = 0; t < 4; ++t) {
    int j = lane + t * 64;
    if (j < R) { v[t] = expf(v[t] - mx); s += v[t]; }
  }
#pragma unroll
  for (int o = 32; o; o >>= 1) s += __shfl_xor(s, o);
  float inv = 1.f / s;
#pragma unroll
  for (int t = 0; t < 4; ++t) {
    int j = lane + t * 64;
    if (j < R) row[j] = f2bfu(v[t] * inv);
  }
}

// out[idx] = inv * sum_g S[g*RR + idx] (bf16 in, fp32 out)
__global__ void meang_bf16(const unsigned short* __restrict__ S, float* __restrict__ out,
                           int RR, int G, float inv)
{
  int idx = blockIdx.x * TPB + threadIdx.x;
  if (idx >= RR) return;
  const unsigned short* p = S + idx;
  float s = 0.f;
  for (int g = 0; g < G; ++g) s += bfu2f(p[(long)g * RR]);
  out[idx] = s * inv;
}

__global__ __launch_bounds__(64) void pool_mean_kernel(const float* __restrict__ X,
                                                       float* __restrict__ out, int R)
{
  int g = blockIdx.x, lane = threadIdx.x;
  const float* p = X + (long)g * R * 64 + lane;
  float s = 0.f;
  for (int r = 0; r < R; ++r) s += p[(long)r * 64];
  out[g * 64 + lane] = s * (1.f / R);
}

__global__ __launch_bounds__(64) void sub_mean_kernel(const float* __restrict__ X,
                                                      const int* __restrict__ sub,
                                                      float* __restrict__ out, int V)
{
  int g = blockIdx.x, lane = threadIdx.x;
  float s = 0.f;
  for (int v = 0; v < V; ++v) {
    int idx = sub[g * V + v];
    s += X[(long)idx * 64 + lane];
  }
  out[g * 64 + lane] = s * (1.f / V);
}

__global__ __launch_bounds__(64) void norm_rows_kernel(const float* __restrict__ X,
                                                       float* __restrict__ Y)
{
  int g = blockIdx.x, lane = threadIdx.x;
  float x = X[g * 64 + lane];
  float ss = x * x;
#pragma unroll
  for (int o = 32; o; o >>= 1) ss += __shfl_xor(ss, o);
  float n = fmaxf(sqrtf(ss), 1e-12f);
  Y[g * 64 + lane] = x / n;
}

__global__ __launch_bounds__(256) void closs_kernel(const float* __restrict__ An,
                                                    const float* __restrict__ Bn,
                                                    float* __restrict__ loss, int G,
                                                    float invTemp, float coef)
{
  int i = blockIdx.x;
  __shared__ float arow[64];
  __shared__ float logits[512];
  __shared__ float red[256];
  int t = threadIdx.x;
  if (t < 64) arow[t] = An[i * 64 + t];
  __syncthreads();
  for (int j = t; j < G; j += 256) {
    const float* bp = Bn + (long)j * 64;
    float d = 0.f;
#pragma unroll
    for (int k = 0; k < 64; ++k) d = fmaf(arow[k], bp[k], d);
    logits[j] = d * invTemp;
  }
  __syncthreads();
  float mx = -1e30f;
  for (int j = t; j < G; j += 256) mx = fmaxf(mx, logits[j]);
  red[t] = mx; __syncthreads();
  for (int o = 128; o; o >>= 1) { if (t < o) red[t] = fmaxf(red[t], red[t + o]); __syncthreads(); }
  mx = red[0]; __syncthreads();
  float s = 0.f;
  for (int j = t; j < G; j += 256) s += expf(logits[j] - mx);
  red[t] = s; __syncthreads();
  for (int o = 128; o; o >>= 1) { if (t < o) red[t] += red[t + o]; __syncthreads(); }
  if (t == 0) {
    float lse = mx + logf(red[0]);
    atomicAdd(loss, coef * (lse - logits[i]));
  }
}

__global__ __launch_bounds__(128) void head_kernel(
    const float* __restrict__ s1, const float* __restrict__ z1,
    const float* __restrict__ s2, const float* __restrict__ z2,
    const float* __restrict__ W1, const float* __restrict__ b1,
    const float* __restrict__ W2, const float* __restrict__ b2,
    float* __restrict__ out)
{
  int g = blockIdx.x, t = threadIdx.x;
  __shared__ float feat[256];
  __shared__ float hid[128];
  if (t < 64) {
    feat[t]       = s1[g * 64 + t];
    feat[64 + t]  = z1[g * 64 + t];
    feat[128 + t] = s2[g * 64 + t];
    feat[192 + t] = z2[g * 64 + t];
  }
  __syncthreads();
  float acc = b1[t];
  for (int k = 0; k < 256; ++k) acc = fmaf(feat[k], W1[k * 128 + t], acc);
  hid[t] = mish_f(acc);
  __syncthreads();
  if (t < 2) {
    float a2 = b2[t];
#pragma unroll
    for (int k = 0; k < 128; ++k) a2 = fmaf(hid[k], W2[k * 2 + t], a2);
    out[g * 2 + t] = a2;
  }
}

extern "C" void kernel_launch(void* const* d_in, const int* in_sizes, int n_in,
                              void* d_out, int out_size, void* d_ws, size_t ws_size,
                              hipStream_t stream)
{
  const float* x1     = (const float*)d_in[0];
  const float* x2     = (const float*)d_in[1];
  const float* fcl_W  = (const float*)d_in[2];  const float* fcl_b  = (const float*)d_in[3];
  const float* fcr_W  = (const float*)d_in[4];  const float* fcr_b  = (const float*)d_in[5];
  const float* fcl1_W = (const float*)d_in[6];  const float* fcl1_b = (const float*)d_in[7];
  const float* fcr1_W = (const float*)d_in[8];  const float* fcr1_b = (const float*)d_in[9];
  const float* a1qW = (const float*)d_in[10]; const float* a1qb = (const float*)d_in[11];
  const float* a1kW = (const float*)d_in[12]; const float* a1kb = (const float*)d_in[13];
  const float* a1vW = (const float*)d_in[14]; const float* a1vb = (const float*)d_in[15];
  const float* a2qW = (const float*)d_in[16]; const float* a2qb = (const float*)d_in[17];
  const float* a2kW = (const float*)d_in[18]; const float* a2kb = (const float*)d_in[19];
  const float* a2vW = (const float*)d_in[20]; const float* a2vb = (const float*)d_in[21];
  const float* convW  = (const float*)d_in[22]; const float* convb  = (const float*)d_in[23];
  const float* conv1W = (const float*)d_in[24]; const float* conv1b = (const float*)d_in[25];
  const float* mlpW   = (const float*)d_in[26]; const float* mlpb   = (const float*)d_in[27];
  const float* fc1aW  = (const float*)d_in[28]; const float* fc1ab  = (const float*)d_in[29];
  const float* fc1bW  = (const float*)d_in[30]; const float* fc1bb  = (const float*)d_in[31];
  const int* ei1  = (const int*)d_in[32];
  const int* ei2  = (const int*)d_in[33];
  const int* sub1 = (const int*)d_in[36];
  const int* sub2 = (const int*)d_in[37];

  const int R1 = in_sizes[6] / 128;       // 200
  const int R2 = in_sizes[8] / 128;       // 160
  const int N1 = in_sizes[34];            // 102400
  const int N2 = in_sizes[35];            // 81920
  const int G  = N1 / R1;                 // 512
  const int E1 = in_sizes[32] / 2, E2 = in_sizes[33] / 2;
  const int EPG1 = E1 / G, EPG2 = E2 / G;
  const int V = in_sizes[36] / G;

  // workspace layout (floats)
  float* W1 = (float*)d_ws;
  size_t w1sz = (size_t)N1 * 128;
  float* W2 = W1 + w1sz;                   // W2..W4 = contiguous N1*192 (QKV)
  float* W3 = W2 + (size_t)N1 * 64;
  float* W4 = W3 + (size_t)N1 * 64;
  float* W5 = W4 + (size_t)N1 * 64;
  float* Pz1 = W5 + (size_t)N1 * 64;
  float* Pz2 = Pz1 + (size_t)G * 64;
  float* Ps1 = Pz2 + (size_t)G * 64;
  float* Ps2 = Ps1 + (size_t)G * 64;
  float* Mt  = Ps2 + (size_t)G * 64;
  float* n_s1 = Mt  + (size_t)G * 64;
  float* n_z2 = n_s1 + (size_t)G * 64;
  float* n_z1 = n_z2 + (size_t)G * 64;
  float* n_s2 = n_z1 + (size_t)G * 64;

  // QKV weight concat buffers: alias Mt..n_s1 (only used before GCN phase)
  float* Wc1 = Mt;                 // 128*192
  float* bc1 = Wc1 + 128 * 192;    // 192
  float* Wc2 = bc1 + 192;          // 128*192
  float* bc2 = Wc2 + 128 * 192;    // 192  (total 49536 < 2*G*64 = 65536)

  float* loss = (float*)d_out;
  float* outp = loss + 1;
  float* aw1  = outp + (size_t)G * 2;
  float* aw2  = aw1 + (size_t)R1 * R1;

  hipMemsetAsync(d_out, 0, sizeof(float), stream);

  concat3_kernel<<<(128 * 192 + TPB - 1) / TPB, TPB, 0, stream>>>(
      a1qW, a1kW, a1vW, Wc1, a1qb, a1kb, a1vb, bc1, 128, 64);
  concat3_kernel<<<(128 * 192 + TPB - 1) / TPB, TPB, 0, stream>>>(
      a2qW, a2kW, a2vW, Wc2, a2qb, a2kb, a2vb, bc2, 128, 64);

  // ======== attention branch, side 1 ========
  gemm_f(stream, x1, fcl1_W, fcl1_b, W1, N1, 128, R1, R1 + 3, 128, 128, 0, 0, 0, 1, 1.f);
  gemm_f(stream, W1, Wc1, bc1, W2, N1, 192, 128, 128, 192, 192, 0, 0, 0, 1, 1.f);
  unsigned short* S1 = (unsigned short*)W1;   // z dead; reuse as bf16 scores
  gemm_scores(stream, W2, W2 + 64, S1, R1, 192, G, 0.125f);
  {
    long rows = (long)G * R1;
    softmax_bf16<<<(int)((rows + 3) / 4), 256, 0, stream>>>(S1, R1, rows);
    meang_bf16<<<(R1 * R1 + TPB - 1) / TPB, TPB, 0, stream>>>(S1, aw1, R1 * R1, G, 1.f / G);
  }
  gemm_pv(stream, S1, W2 + 128, W5, R1, 192, G);
  pool_mean_kernel<<<G, 64, 0, stream>>>(W5, Pz1, R1);

  // ======== attention branch, side 2 ========
  gemm_f(stream, x2, fcr1_W, fcr1_b, W1, N2, 128, R2, R2 + 3, 128, 128, 0, 0, 0, 1, 1.f);
  gemm_f(stream, W1, Wc2, bc2, W2, N2, 192, 128, 128, 192, 192, 0, 0, 0, 1, 1.f);
  unsigned short* S2 = (unsigned short*)W1;
  gemm_scores(stream, W2, W2 + 64, S2, R2, 192, G, 0.125f);
  {
    long rows = (long)G * R2;
    softmax_bf16<<<(int)((rows + 3) / 4), 256, 0, stream>>>(S2, R2, rows);
    meang_bf16<<<(R2 * R2 + TPB - 1) / TPB, TPB, 0, stream>>>(S2, aw2, R2 * R2, G, 1.f / G);
  }
  gemm_pv(stream, S2, W2 + 128, W5, R2, 192, G);
  pool_mean_kernel<<<G, 64, 0, stream>>>(W5, Pz2, R2);

  // ======== GCN branch, side 1 ========
  gemm_f(stream, x1, fcl_W, fcl_b, W1, N1, 128, R1 + 3, R1 + 3, 128, 128, 0, 0, 0, 1, 1.f);
  gemm_f(stream, W1, convW, nullptr, W2, N1, 64, 128, 128, 64, 64, 0, 0, 0, 1, 1.f);
  gcn_kernel<<<G, 256, 0, stream>>>(W2, ei1, ei1 + E1, convb, W3, R1, EPG1, 1);
  gemm_f(stream, W3, conv1W, nullptr, W2, N1, 64, 64, 64, 64, 64, 0, 0, 0, 1, 1.f);
  gcn_kernel<<<G, 256, 0, stream>>>(W2, ei1, ei1 + E1, conv1b, W4, R1, EPG1, 0);
  sub_mean_kernel<<<G, 64, 0, stream>>>(W4, sub1, Mt, V);
  gemm_f(stream, Mt, mlpW, mlpb, Ps1, G, 64, 64, 64, 64, 64, 0, 0, 0, 1, 1.f);

  // ======== GCN branch, side 2 ========
  gemm_f(stream, x2, fcr_W, fcr_b, W1, N2, 128, R2 + 3, R2 + 3, 128, 128, 0, 0, 0, 1, 1.f);
  gemm_f(stream, W1, convW, nullptr, W2, N2, 64, 128, 128, 64, 64, 0, 0, 0, 1, 1.f);
  gcn_kernel<<<G, 256, 0, stream>>>(W2, ei2, ei2 + E2, convb, W3, R2, EPG2, 1);
  gemm_f(stream, W3, conv1W, nullptr, W2, N2, 64, 64, 64, 64, 64, 0, 0, 0, 1, 1.f);
  gcn_kernel<<<G, 256, 0, stream>>>(W2, ei2, ei2 + E2, conv1b, W4, R2, EPG2, 0);
  sub_mean_kernel<<<G, 64, 0, stream>>>(W4, sub2, Mt, V);
  gemm_f(stream, Mt, mlpW, mlpb, Ps2, G, 64, 64, 64, 64, 64, 0, 0, 0, 1, 1.f);

  // ======== contrastive loss + head ========
  norm_rows_kernel<<<G, 64, 0, stream>>>(Ps1, n_s1);
  norm_rows_kernel<<<G, 64, 0, stream>>>(Pz2, n_z2);
  norm_rows_kernel<<<G, 64, 0, stream>>>(Pz1, n_z1);
  norm_rows_kernel<<<G, 64, 0, stream>>>(Ps2, n_s2);
  const float invTemp = 1.f / 0.6f;
  closs_kernel<<<G, 256, 0, stream>>>(n_s1, n_z2, loss, G, invTemp, 1.f / G);
  closs_kernel<<<G, 256, 0, stream>>>(n_z1, n_s2, loss, G, invTemp, 1.f / G);

  head_kernel<<<G, 128, 0, stream>>>(Ps1, Pz1, Ps2, Pz2, fc1aW, fc1ab, fc1bW, fc1bb, outp);
}